// Round 5
// baseline (377.619 us; speedup 1.0000x reference)
//
#include <hip/hip_runtime.h>

#define HEADS 8
#define Bq 4
#define Nq 2048
#define Dq 512
#define Hq 2048

typedef __bf16 bf16;
typedef __bf16 bf16x8 __attribute__((ext_vector_type(8)));
typedef float f32x4 __attribute__((ext_vector_type(4)));

__device__ __forceinline__ void gload16(const bf16* g, bf16* s) {
  __builtin_amdgcn_global_load_lds(
      (const __attribute__((address_space(1))) void*)g,
      (__attribute__((address_space(3))) void*)s, 16, 0, 0);
}

// ---------------- fp32 -> bf16 elementwise convert ----------------
__global__ __launch_bounds__(256) void k_cvt_bf16(const float* __restrict__ in,
                                                  bf16* __restrict__ out, int n) {
  int i = (blockIdx.x * 256 + threadIdx.x) * 4;
  if (i >= n) return;
  float4 v = *(const float4*)(in + i);
  union { bf16 h[4]; ushort4 u; } r;
  r.h[0] = (bf16)v.x; r.h[1] = (bf16)v.y; r.h[2] = (bf16)v.z; r.h[3] = (bf16)v.w;
  *(ushort4*)(out + i) = r.u;
}

// ---------------- transpose + convert: in fp32 [K][N] -> out bf16 [N][K] ----------------
__global__ __launch_bounds__(256) void k_transpose_cvt(const float* __restrict__ in,
                                                       bf16* __restrict__ out,
                                                       int K, int N) {
  __shared__ float t[32][33];
  const int n0 = blockIdx.x * 32, k0 = blockIdx.y * 32;
  const int tx = threadIdx.x, ty = threadIdx.y;
#pragma unroll
  for (int j = 0; j < 32; j += 8)
    t[ty + j][tx] = in[(size_t)(k0 + ty + j) * N + n0 + tx];
  __syncthreads();
#pragma unroll
  for (int j = 0; j < 32; j += 8)
    out[(size_t)(n0 + ty + j) * K + k0 + tx] = (bf16)t[tx][ty + j];
}

// ---------------- GEMM: C[M][N] = A[M][K](bf16) * BT[N][K]^T + bias ----------------
// 128x128 tile, BK=64, 256 thr = 4 waves (2x2). global_load_lds width-16 staging,
// double-buffered 2-phase. Swizzle per rule #21: linear dest + inverse-XOR global
// source + XOR on ds_read -> conflict-free b128.
// VTOUT: blocks with n0>=1024 (V of qkv) store TRANSPOSED into vt[B*H][64][Nq].
template <bool GELU, bool RESID, bool STORE_BF16, bool VTOUT>
__global__ __launch_bounds__(256) void k_gemm(const bf16* __restrict__ A,
                                              const bf16* __restrict__ BT,
                                              const float* __restrict__ bias,
                                              const float* __restrict__ resid,
                                              void* __restrict__ Cout,
                                              bf16* __restrict__ vt,
                                              int M, int N, int K) {
  __shared__ bf16 As[2][128 * 64];
  __shared__ bf16 Bs[2][128 * 64];
  const int m0 = blockIdx.y * 128, n0 = blockIdx.x * 128;
  const int tid = threadIdx.x, lane = tid & 63, wid = tid >> 6;
  const int wr = wid >> 1, wc = wid & 1;
  const int r16 = lane & 15, g = lane >> 4;

  const int srow = (lane >> 3);            // 0..7 within instr
  const int schunk = (lane & 7) ^ srow;    // inverse-swizzled source chunk

  f32x4 acc[4][4] = {};

  const int NT = K >> 6;
#pragma unroll
  for (int i = 0; i < 4; i++) {
    int rl = wid * 32 + i * 8 + srow;
    gload16(A + (size_t)(m0 + rl) * K + schunk * 8, &As[0][(wid * 32 + i * 8) * 64]);
    gload16(BT + (size_t)(n0 + rl) * K + schunk * 8, &Bs[0][(wid * 32 + i * 8) * 64]);
  }
  __syncthreads();

  for (int t = 0; t < NT; t++) {
    const int cur = t & 1;
    if (t + 1 < NT) {
      const int kt = (t + 1) << 6;
#pragma unroll
      for (int i = 0; i < 4; i++) {
        int rl = wid * 32 + i * 8 + srow;
        gload16(A + (size_t)(m0 + rl) * K + kt + schunk * 8,
                &As[cur ^ 1][(wid * 32 + i * 8) * 64]);
        gload16(BT + (size_t)(n0 + rl) * K + kt + schunk * 8,
                &Bs[cur ^ 1][(wid * 32 + i * 8) * 64]);
      }
    }
    const bf16* Ab = As[cur];
    const bf16* Bb = Bs[cur];
#pragma unroll
    for (int kk = 0; kk < 2; kk++) {
      bf16x8 af[4], bfr[4];
#pragma unroll
      for (int mi = 0; mi < 4; mi++) {
        int row = wr * 64 + mi * 16 + r16;
        af[mi] = *(const bf16x8*)(Ab + row * 64 + (((4 * kk + g) ^ (row & 7)) * 8));
      }
#pragma unroll
      for (int ni = 0; ni < 4; ni++) {
        int row = wc * 64 + ni * 16 + r16;
        bfr[ni] = *(const bf16x8*)(Bb + row * 64 + (((4 * kk + g) ^ (row & 7)) * 8));
      }
#pragma unroll
      for (int mi = 0; mi < 4; mi++)
#pragma unroll
        for (int ni = 0; ni < 4; ni++)
          acc[mi][ni] = __builtin_amdgcn_mfma_f32_16x16x32_bf16(af[mi], bfr[ni],
                                                                acc[mi][ni], 0, 0, 0);
    }
    __syncthreads();
  }

  if (VTOUT && n0 >= 1024) {
#pragma unroll
    for (int mi = 0; mi < 4; mi++)
#pragma unroll
      for (int ni = 0; ni < 4; ni++) {
        int col = n0 + wc * 64 + ni * 16 + r16;
        int vd = col - 1024;
        int hh = vd >> 6, e = vd & 63;
        float bv = bias[col];
        int row0 = m0 + wr * 64 + mi * 16 + 4 * g;
        int bb = row0 >> 11, n = row0 & 2047;
        union { bf16 h[4]; ushort4 u; } r4;
#pragma unroll
        for (int r = 0; r < 4; r++) r4.h[r] = (bf16)(acc[mi][ni][r] + bv);
        *(ushort4*)(vt + ((size_t)(bb * HEADS + hh) * 64 + e) * Nq + n) = r4.u;
      }
    return;
  }

#pragma unroll
  for (int mi = 0; mi < 4; mi++)
#pragma unroll
    for (int ni = 0; ni < 4; ni++) {
      int col = n0 + wc * 64 + ni * 16 + r16;
      float bv = bias[col];
#pragma unroll
      for (int r = 0; r < 4; r++) {
        int row = m0 + wr * 64 + mi * 16 + 4 * g + r;
        float v = acc[mi][ni][r] + bv;
        if (GELU) v = 0.5f * v * (1.f + erff(v * 0.70710678118654752f));
        if (RESID) v += resid[(size_t)row * N + col];
        if (STORE_BF16) ((bf16*)Cout)[(size_t)row * N + col] = (bf16)v;
        else            ((float*)Cout)[(size_t)row * N + col] = v;
      }
    }
}

// ---------------- flash attention: no-LDS, swapped-QK^T, 16 q-rows/wave ----------------
// grid (B*H, Nq/64): bh on x so all q-blocks of one (b,h) share an XCD L2.
// K,V frags loaded DIRECTLY global->VGPR (L1/L2-resident: 512KB per (b,h)).
// No barriers, no LDS staging. P-redistribution via permlane32_swap + xor16.
__global__ __launch_bounds__(256) void k_attn(const bf16* __restrict__ qkv,
                                              const bf16* __restrict__ vt,
                                              bf16* __restrict__ att) {
  const int qt = blockIdx.y, b = blockIdx.x >> 3, h = blockIdx.x & 7;
  const int tid = threadIdx.x, lane = tid & 63, wid = tid >> 6;
  const int r16 = lane & 15, g = lane >> 4;
  const size_t base = (size_t)b * Nq * (3 * Dq);
  const bf16* qp = qkv + base + h * 64;
  const bf16* kp = qkv + base + Dq + h * 64;
  const bf16* vtp = vt + (size_t)(b * HEADS + h) * 64 * Nq;
  const int q0 = qt * 64 + wid * 16;

  bf16x8 qf[2];
#pragma unroll
  for (int kk = 0; kk < 2; kk++)
    qf[kk] = *(const bf16x8*)(qp + (size_t)(q0 + r16) * (3 * Dq) + kk * 32 + g * 8);

  f32x4 o[4] = {};
  float mrun = -INFINITY, lrun = 0.f;

  for (int kv0 = 0; kv0 < Nq; kv0 += 64) {
    // K frags direct from global: kf[kk][nt] = K[kv0+nt*16+r16][kk*32+g*8..+7]
    bf16x8 kf[2][4];
#pragma unroll
    for (int kk = 0; kk < 2; kk++)
#pragma unroll
      for (int nt = 0; nt < 4; nt++)
        kf[kk][nt] = *(const bf16x8*)(kp + (size_t)(kv0 + nt * 16 + r16) * (3 * Dq) +
                                      kk * 32 + g * 8);

    // S^T[kv][q]: s[nt]
    f32x4 s[4] = {};
#pragma unroll
    for (int kk = 0; kk < 2; kk++)
#pragma unroll
      for (int nt = 0; nt < 4; nt++)
        s[nt] = __builtin_amdgcn_mfma_f32_16x16x32_bf16(kf[kk][nt], qf[kk], s[nt], 0, 0, 0);

    // V frags direct from global (issue early; independent of softmax)
    bf16x8 vf[2][4];
#pragma unroll
    for (int kk = 0; kk < 2; kk++)
#pragma unroll
      for (int ot = 0; ot < 4; ot++)
        vf[kk][ot] = *(const bf16x8*)(vtp + (size_t)(ot * 16 + r16) * Nq + kv0 +
                                      kk * 32 + g * 8);

    // online softmax with defer-max (THR=8)
    float mx = s[0][0];
#pragma unroll
    for (int nt = 0; nt < 4; nt++)
#pragma unroll
      for (int r = 0; r < 4; r++) mx = fmaxf(mx, s[nt][r]);
    mx = fmaxf(mx, __shfl_xor(mx, 16));
    mx = fmaxf(mx, __shfl_xor(mx, 32));
    const float mold = mrun;
    const bool need = (mx > mold + 8.f);
    const float mn = need ? mx : mold;
    mrun = mn;
    float rs = 0.f;
#pragma unroll
    for (int nt = 0; nt < 4; nt++)
#pragma unroll
      for (int r = 0; r < 4; r++) {
        float pv = __expf(s[nt][r] - mn);
        s[nt][r] = pv;
        rs += pv;
      }
    rs += __shfl_xor(rs, 16);
    rs += __shfl_xor(rs, 32);
    const float scale = need ? __expf(mold - mn) : 1.f;
    lrun = need ? lrun * scale + rs : lrun + rs;

    if (__any(need)) {
      float so[4];
#pragma unroll
      for (int r = 0; r < 4; r++) so[r] = __shfl(scale, 4 * g + r);
#pragma unroll
      for (int ot = 0; ot < 4; ot++)
#pragma unroll
        for (int r = 0; r < 4; r++) o[ot][r] *= so[r];
    }

    // pack P^T to bf16 pairs: packed[nt][p] = (reg 2p, 2p+1)
    unsigned packed[4][2];
#pragma unroll
    for (int nt = 0; nt < 4; nt++)
#pragma unroll
      for (int p = 0; p < 2; p++) {
        union { bf16 h[2]; unsigned u; } pk;
        pk.h[0] = (bf16)s[nt][2 * p];
        pk.h[1] = (bf16)s[nt][2 * p + 1];
        packed[nt][p] = pk.u;
      }

    // PV A-frag routing: dest g word w = packed[2kk+(g>>1)][w&1] @ lane g'=2(g&1)+(w>>1).
    // permlane32_swap splits X/Y lo/hi g-halves; xor16 does the within-half swap.
#pragma unroll
    for (int kk = 0; kk < 2; kk++) {
      unsigned a0 = packed[2 * kk][0], b0 = packed[2 * kk + 1][0];
      unsigned a1 = packed[2 * kk][1], b1 = packed[2 * kk + 1][1];
      asm volatile("v_permlane32_swap_b32 %0, %1" : "+v"(a0), "+v"(b0));
      asm volatile("v_permlane32_swap_b32 %0, %1" : "+v"(a1), "+v"(b1));
      unsigned z10 = __shfl_xor((int)a0, 16);
      unsigned z11 = __shfl_xor((int)a1, 16);
      unsigned z20 = __shfl_xor((int)b0, 16);
      unsigned z21 = __shfl_xor((int)b1, 16);
      union { unsigned w[4]; bf16x8 v; } pa;
      const bool ghi = (g & 1);
      pa.w[0] = ghi ? z20 : a0;
      pa.w[1] = ghi ? z21 : a1;
      pa.w[2] = ghi ? b0 : z10;
      pa.w[3] = ghi ? b1 : z11;
#pragma unroll
      for (int ot = 0; ot < 4; ot++)
        o[ot] = __builtin_amdgcn_mfma_f32_16x16x32_bf16(pa.v, vf[kk][ot], o[ot], 0, 0, 0);
    }
  }

  // epilogue: O row=q=4g+r, col=e=r16; l lives on lane r16=q -> shfl
  float li[4];
#pragma unroll
  for (int r = 0; r < 4; r++) li[r] = 0.125f / __shfl(lrun, 4 * g + r);
#pragma unroll
  for (int ot = 0; ot < 4; ot++)
#pragma unroll
    for (int r = 0; r < 4; r++) {
      int row = q0 + 4 * g + r;
      int col = h * 64 + ot * 16 + r16;
      att[((size_t)b * Nq + row) * Dq + col] = (bf16)(o[ot][r] * li[r]);
    }
}

// ---------------- LayerNorm over D=512, one wave per row ----------------
template <bool WB>
__global__ __launch_bounds__(64) void k_ln(const float* __restrict__ in,
                                           const float* __restrict__ gamma,
                                           const float* __restrict__ beta,
                                           float* __restrict__ outf,
                                           bf16* __restrict__ outb) {
  const int row = blockIdx.x, lane = threadIdx.x;
  const float* p = in + (size_t)row * Dq + lane * 8;
  float4 a = *(const float4*)p;
  float4 c = *(const float4*)(p + 4);
  float vals[8] = {a.x, a.y, a.z, a.w, c.x, c.y, c.z, c.w};
  float s = 0.f, q = 0.f;
#pragma unroll
  for (int j = 0; j < 8; j++) { s += vals[j]; q += vals[j] * vals[j]; }
#pragma unroll
  for (int off = 1; off < 64; off <<= 1) {
    s += __shfl_xor(s, off);
    q += __shfl_xor(q, off);
  }
  float mean = s * (1.f / Dq);
  float var = q * (1.f / Dq) - mean * mean;
  float rstd = rsqrtf(var + 1e-5f);
  float of[8];
#pragma unroll
  for (int j = 0; j < 8; j++) {
    int col = lane * 8 + j;
    of[j] = (vals[j] - mean) * rstd * gamma[col] + beta[col];
  }
  float4* op = (float4*)(outf + (size_t)row * Dq + lane * 8);
  op[0] = make_float4(of[0], of[1], of[2], of[3]);
  op[1] = make_float4(of[4], of[5], of[6], of[7]);
  if (WB) {
    union { bf16 h[8]; ushort4 u[2]; } rr;
#pragma unroll
    for (int j = 0; j < 8; j++) rr.h[j] = (bf16)of[j];
    ushort4* ob = (ushort4*)(outb + (size_t)row * Dq + lane * 8);
    ob[0] = rr.u[0];
    ob[1] = rr.u[1];
  }
}

extern "C" void kernel_launch(void* const* d_in, const int* in_sizes, int n_in,
                              void* d_out, int out_size, void* d_ws, size_t ws_size,
                              hipStream_t stream) {
  const float* x      = (const float*)d_in[0];
  const float* w_qkv  = (const float*)d_in[1];
  const float* b_qkv  = (const float*)d_in[2];
  const float* w_proj = (const float*)d_in[3];
  const float* b_proj = (const float*)d_in[4];
  const float* ln1_g  = (const float*)d_in[5];
  const float* ln1_b  = (const float*)d_in[6];
  const float* w1     = (const float*)d_in[7];
  const float* b1     = (const float*)d_in[8];
  const float* w2     = (const float*)d_in[9];
  const float* b2     = (const float*)d_in[10];
  const float* ln2_g  = (const float*)d_in[11];
  const float* ln2_b  = (const float*)d_in[12];
  float* out = (float*)d_out;

  const int M = Bq * Nq;  // 8192 rows

  char* p = (char*)d_ws;
  auto alloc = [&](size_t bytes) -> void* {
    char* r = p;
    p += (bytes + 255) & ~(size_t)255;
    return (void*)r;
  };
  bf16* xb     = (bf16*)alloc((size_t)M * Dq * 2);        // x bf16; later reused as att
  bf16* qkvb   = (bf16*)alloc((size_t)M * 3 * Dq * 2);
  bf16* wqkvT  = (bf16*)alloc((size_t)3 * Dq * Dq * 2);
  bf16* wprojT = (bf16*)alloc((size_t)Dq * Dq * 2);
  bf16* w1T    = (bf16*)alloc((size_t)Hq * Dq * 2);
  bf16* w2T    = (bf16*)alloc((size_t)Dq * Hq * 2);
  float* y1    = (float*)alloc((size_t)M * Dq * 4);       // also y2
  float* x1f   = (float*)alloc((size_t)M * Dq * 4);
  bf16* x1b    = (bf16*)alloc((size_t)M * Dq * 2);
  bf16* hb     = (bf16*)alloc((size_t)M * Hq * 2);
  bf16* attb   = xb;   // alias: xb consumed by qkv GEMM before attention writes
  bf16* vtb    = hb;   // alias: hb written by ffn1 only after attention is done

  dim3 tb(32, 8);
  k_cvt_bf16<<<(M * Dq / 4 + 255) / 256, 256, 0, stream>>>(x, xb, M * Dq);
  k_transpose_cvt<<<dim3((3 * Dq) / 32, Dq / 32), tb, 0, stream>>>(w_qkv, wqkvT, Dq, 3 * Dq);
  k_transpose_cvt<<<dim3(Dq / 32, Dq / 32), tb, 0, stream>>>(w_proj, wprojT, Dq, Dq);
  k_transpose_cvt<<<dim3(Hq / 32, Dq / 32), tb, 0, stream>>>(w1, w1T, Dq, Hq);
  k_transpose_cvt<<<dim3(Dq / 32, Hq / 32), tb, 0, stream>>>(w2, w2T, Hq, Dq);

  // qkv = x @ w_qkv + b_qkv  (Q,K -> qkvb natural; V -> vtb transposed)
  k_gemm<false, false, true, true><<<dim3((3 * Dq) / 128, M / 128), 256, 0, stream>>>(
      xb, wqkvT, b_qkv, nullptr, qkvb, vtb, M, 3 * Dq, Dq);
  // attention (bh on grid-x: one (b,h) per XCD-group for L2 locality)
  k_attn<<<dim3(Bq * HEADS, Nq / 64), 256, 0, stream>>>(qkvb, vtb, attb);
  // y1 = att @ w_proj + b_proj + x
  k_gemm<false, true, false, false><<<dim3(Dq / 128, M / 128), 256, 0, stream>>>(
      attb, wprojT, b_proj, x, y1, nullptr, M, Dq, Dq);
  // x1 = LN1(y1) -> fp32 + bf16
  k_ln<true><<<M, 64, 0, stream>>>(y1, ln1_g, ln1_b, x1f, x1b);
  // h = gelu(x1 @ w1 + b1)
  k_gemm<true, false, true, false><<<dim3(Hq / 128, M / 128), 256, 0, stream>>>(
      x1b, w1T, b1, nullptr, hb, nullptr, M, Hq, Dq);
  // y2 = h @ w2 + b2 + x1
  k_gemm<false, true, false, false><<<dim3(Dq / 128, M / 128), 256, 0, stream>>>(
      hb, w2T, b2, x1f, y1, nullptr, M, Dq, Hq);
  // out = LN2(y2)
  k_ln<false><<<M, 64, 0, stream>>>(y1, ln2_g, ln2_b, out, nullptr);
}

// Round 6
// 223.520 us; speedup vs baseline: 1.6894x; 1.6894x over previous
//
#include <hip/hip_runtime.h>

#define HEADS 8
#define Bq 4
#define Nq 2048
#define Dq 512
#define Hq 2048

typedef __bf16 bf16;
typedef __bf16 bf16x8 __attribute__((ext_vector_type(8)));
typedef __bf16 bf16x4 __attribute__((ext_vector_type(4)));
typedef short short4v __attribute__((ext_vector_type(4)));
typedef float f32x4 __attribute__((ext_vector_type(4)));

__device__ __forceinline__ void gload16(const bf16* g, bf16* s) {
  __builtin_amdgcn_global_load_lds(
      (const __attribute__((address_space(1))) void*)g,
      (__attribute__((address_space(3))) void*)s, 16, 0, 0);
}

// 16x16x16 bf16 MFMA (legacy shape; A/B = 4 bf16 = 2 VGPR, k = 4g..4g+3 per lane)
__device__ __forceinline__ f32x4 mfma16(bf16x4 a, bf16x4 b, f32x4 c) {
#if __has_builtin(__builtin_amdgcn_mfma_f32_16x16x16bf16_1k)
  return __builtin_amdgcn_mfma_f32_16x16x16bf16_1k(
      __builtin_bit_cast(short4v, a), __builtin_bit_cast(short4v, b), c, 0, 0, 0);
#else
  f32x4 d = c;
  asm("v_mfma_f32_16x16x16_bf16 %0, %1, %2, %0" : "+v"(d) : "v"(a), "v"(b));
  return d;
#endif
}

// ---------------- fp32 -> bf16 elementwise convert ----------------
__global__ __launch_bounds__(256) void k_cvt_bf16(const float* __restrict__ in,
                                                  bf16* __restrict__ out, int n) {
  int i = (blockIdx.x * 256 + threadIdx.x) * 4;
  if (i >= n) return;
  float4 v = *(const float4*)(in + i);
  union { bf16 h[4]; ushort4 u; } r;
  r.h[0] = (bf16)v.x; r.h[1] = (bf16)v.y; r.h[2] = (bf16)v.z; r.h[3] = (bf16)v.w;
  *(ushort4*)(out + i) = r.u;
}

// ---------------- transpose + convert: in fp32 [K][N] -> out bf16 [N][K] ----------------
__global__ __launch_bounds__(256) void k_transpose_cvt(const float* __restrict__ in,
                                                       bf16* __restrict__ out,
                                                       int K, int N) {
  __shared__ float t[32][33];
  const int n0 = blockIdx.x * 32, k0 = blockIdx.y * 32;
  const int tx = threadIdx.x, ty = threadIdx.y;
#pragma unroll
  for (int j = 0; j < 32; j += 8)
    t[ty + j][tx] = in[(size_t)(k0 + ty + j) * N + n0 + tx];
  __syncthreads();
#pragma unroll
  for (int j = 0; j < 32; j += 8)
    out[(size_t)(n0 + ty + j) * K + k0 + tx] = (bf16)t[tx][ty + j];
}

// ---------------- GEMM: C[M][N] = A[M][K](bf16) * BT[N][K]^T + bias ----------------
// 128x128 tile, BK=64, 4 waves (2x2). global_load_lds staging, double-buffered,
// rule-#21 swizzle. VTOUT: n0>=1024 (V of qkv) stores transposed AND kv-interleaved
// into vt[B*H][64][Nq]: within each 64-kv block, kv=16s+4g+j -> position g*16+s*4+j.
template <bool GELU, bool RESID, bool STORE_BF16, bool VTOUT>
__global__ __launch_bounds__(256) void k_gemm(const bf16* __restrict__ A,
                                              const bf16* __restrict__ BT,
                                              const float* __restrict__ bias,
                                              const float* __restrict__ resid,
                                              void* __restrict__ Cout,
                                              bf16* __restrict__ vt,
                                              int M, int N, int K) {
  __shared__ bf16 As[2][128 * 64];
  __shared__ bf16 Bs[2][128 * 64];
  const int m0 = blockIdx.y * 128, n0 = blockIdx.x * 128;
  const int tid = threadIdx.x, lane = tid & 63, wid = tid >> 6;
  const int wr = wid >> 1, wc = wid & 1;
  const int r16 = lane & 15, g = lane >> 4;

  const int srow = (lane >> 3);
  const int schunk = (lane & 7) ^ srow;

  f32x4 acc[4][4] = {};

  const int NT = K >> 6;
#pragma unroll
  for (int i = 0; i < 4; i++) {
    int rl = wid * 32 + i * 8 + srow;
    gload16(A + (size_t)(m0 + rl) * K + schunk * 8, &As[0][(wid * 32 + i * 8) * 64]);
    gload16(BT + (size_t)(n0 + rl) * K + schunk * 8, &Bs[0][(wid * 32 + i * 8) * 64]);
  }
  __syncthreads();

  for (int t = 0; t < NT; t++) {
    const int cur = t & 1;
    if (t + 1 < NT) {
      const int kt = (t + 1) << 6;
#pragma unroll
      for (int i = 0; i < 4; i++) {
        int rl = wid * 32 + i * 8 + srow;
        gload16(A + (size_t)(m0 + rl) * K + kt + schunk * 8,
                &As[cur ^ 1][(wid * 32 + i * 8) * 64]);
        gload16(BT + (size_t)(n0 + rl) * K + kt + schunk * 8,
                &Bs[cur ^ 1][(wid * 32 + i * 8) * 64]);
      }
    }
    const bf16* Ab = As[cur];
    const bf16* Bb = Bs[cur];
#pragma unroll
    for (int kk = 0; kk < 2; kk++) {
      bf16x8 af[4], bfr[4];
#pragma unroll
      for (int mi = 0; mi < 4; mi++) {
        int row = wr * 64 + mi * 16 + r16;
        af[mi] = *(const bf16x8*)(Ab + row * 64 + (((4 * kk + g) ^ (row & 7)) * 8));
      }
#pragma unroll
      for (int ni = 0; ni < 4; ni++) {
        int row = wc * 64 + ni * 16 + r16;
        bfr[ni] = *(const bf16x8*)(Bb + row * 64 + (((4 * kk + g) ^ (row & 7)) * 8));
      }
#pragma unroll
      for (int mi = 0; mi < 4; mi++)
#pragma unroll
        for (int ni = 0; ni < 4; ni++)
          acc[mi][ni] = __builtin_amdgcn_mfma_f32_16x16x32_bf16(af[mi], bfr[ni],
                                                                acc[mi][ni], 0, 0, 0);
    }
    __syncthreads();
  }

  if (VTOUT && n0 >= 1024) {
#pragma unroll
    for (int mi = 0; mi < 4; mi++)
#pragma unroll
      for (int ni = 0; ni < 4; ni++) {
        int col = n0 + wc * 64 + ni * 16 + r16;
        int vd = col - 1024;
        int hh = vd >> 6, e = vd & 63;
        float bv = bias[col];
        int row0 = m0 + wr * 64 + mi * 16 + 4 * g;
        int bb = row0 >> 11, n = row0 & 2047;
        // kv-local = mi*16+4g; interleaved position = g*16 + mi*4 (+r)
        int ncol = (n & ~63) + g * 16 + mi * 4;
        union { bf16 h[4]; ushort4 u; } r4;
#pragma unroll
        for (int r = 0; r < 4; r++) r4.h[r] = (bf16)(acc[mi][ni][r] + bv);
        *(ushort4*)(vt + ((size_t)(bb * HEADS + hh) * 64 + e) * Nq + ncol) = r4.u;
      }
    return;
  }

#pragma unroll
  for (int mi = 0; mi < 4; mi++)
#pragma unroll
    for (int ni = 0; ni < 4; ni++) {
      int col = n0 + wc * 64 + ni * 16 + r16;
      float bv = bias[col];
#pragma unroll
      for (int r = 0; r < 4; r++) {
        int row = m0 + wr * 64 + mi * 16 + 4 * g + r;
        float v = acc[mi][ni][r] + bv;
        if (GELU) v = 0.5f * v * (1.f + erff(v * 0.70710678118654752f));
        if (RESID) v += resid[(size_t)row * N + col];
        if (STORE_BF16) ((bf16*)Cout)[(size_t)row * N + col] = (bf16)v;
        else            ((float*)Cout)[(size_t)row * N + col] = v;
      }
    }
}

// ---------------- flash attention: O^T = V^T P^T, zero-shuffle PV ----------------
// grid (B*H, Nq/128), 256 thr = 4 waves, 32 q-rows/wave, KVBLK=64.
// S^T = mfma_16x16x32(A=K, B=Q): lane holds P^T[kv=4g+reg][q=r16].
// PV = mfma_16x16x16(A=V^T frag, B=P^T-from-regs): S^T C-layout == B-frag layout.
// O^T: col=q=r16 -> rescale + 1/l need no shuffles. K/V LDS-staged via
// global_load_lds + rule-#21 swizzle, double-buffered, 1 barrier/tile.
__global__ __launch_bounds__(256) void k_attn(const bf16* __restrict__ qkv,
                                              const bf16* __restrict__ vt,
                                              bf16* __restrict__ att) {
  __shared__ bf16 Ks[2][64 * 64];
  __shared__ bf16 Vs[2][64 * 64];
  const int qt = blockIdx.y, b = blockIdx.x >> 3, h = blockIdx.x & 7;
  const int tid = threadIdx.x, lane = tid & 63, wid = tid >> 6;
  const int r16 = lane & 15, g = lane >> 4;
  const size_t base = (size_t)b * Nq * (3 * Dq);
  const bf16* qp = qkv + base + h * 64;
  const bf16* kp = qkv + base + Dq + h * 64;
  const bf16* vtp = vt + (size_t)(b * HEADS + h) * 64 * Nq;
  const int q0 = qt * 128 + wid * 32;

  bf16x8 qf[2][2];
#pragma unroll
  for (int mi = 0; mi < 2; mi++)
#pragma unroll
    for (int kk = 0; kk < 2; kk++)
      qf[mi][kk] = *(const bf16x8*)(qp + (size_t)(q0 + mi * 16 + r16) * (3 * Dq) +
                                    kk * 32 + g * 8);

  const int srow = lane >> 3;
  const int sch = (lane & 7) ^ srow;

  f32x4 o[2][4] = {};
  float mrun[2] = {-INFINITY, -INFINITY}, lrun[2] = {0.f, 0.f};

  // prologue: stage tile 0 into buf 0
#pragma unroll
  for (int i = 0; i < 2; i++) {
    int br = (wid * 2 + i) * 8;
    gload16(kp + (size_t)(br + srow) * (3 * Dq) + sch * 8, &Ks[0][br * 64]);
    gload16(vtp + (size_t)(br + srow) * Nq + sch * 8, &Vs[0][br * 64]);
  }
  __syncthreads();

  const int NTILES = Nq / 64;
  for (int t = 0; t < NTILES; t++) {
    const int c = t & 1;
    if (t + 1 < NTILES) {
      const int kv1 = (t + 1) * 64;
#pragma unroll
      for (int i = 0; i < 2; i++) {
        int br = (wid * 2 + i) * 8;
        gload16(kp + (size_t)(kv1 + br + srow) * (3 * Dq) + sch * 8,
                &Ks[c ^ 1][br * 64]);
        gload16(vtp + (size_t)(br + srow) * Nq + kv1 + sch * 8, &Vs[c ^ 1][br * 64]);
      }
    }

    // S^T[kv][q]: s[nt][mi]
    f32x4 s[4][2] = {};
#pragma unroll
    for (int kk = 0; kk < 2; kk++)
#pragma unroll
      for (int nt = 0; nt < 4; nt++) {
        const bf16x8 kf = *(const bf16x8*)(
            &Ks[c][(nt * 16 + r16) * 64 + (((4 * kk + g) ^ (r16 & 7)) * 8)]);
#pragma unroll
        for (int mi = 0; mi < 2; mi++)
          s[nt][mi] = __builtin_amdgcn_mfma_f32_16x16x32_bf16(kf, qf[mi][kk],
                                                              s[nt][mi], 0, 0, 0);
      }

    // online softmax with defer-max (THR=8); all stats live on lane's q=r16
    float scale[2];
    bool need[2];
#pragma unroll
    for (int mi = 0; mi < 2; mi++) {
      float mx = s[0][mi][0];
#pragma unroll
      for (int nt = 0; nt < 4; nt++)
#pragma unroll
        for (int r = 0; r < 4; r++) mx = fmaxf(mx, s[nt][mi][r]);
      mx = fmaxf(mx, __shfl_xor(mx, 16));
      mx = fmaxf(mx, __shfl_xor(mx, 32));
      const float mold = mrun[mi];
      need[mi] = (mx > mold + 8.f);
      const float mn = need[mi] ? mx : mold;
      mrun[mi] = mn;
      float rs = 0.f;
#pragma unroll
      for (int nt = 0; nt < 4; nt++)
#pragma unroll
        for (int r = 0; r < 4; r++) {
          float pv = __expf(s[nt][mi][r] - mn);
          s[nt][mi][r] = pv;
          rs += pv;
        }
      rs += __shfl_xor(rs, 16);
      rs += __shfl_xor(rs, 32);
      scale[mi] = need[mi] ? __expf(mold - mn) : 1.f;
      lrun[mi] = need[mi] ? lrun[mi] * scale[mi] + rs : lrun[mi] + rs;
    }
    if (__any(need[0] || need[1])) {
#pragma unroll
      for (int mi = 0; mi < 2; mi++)
#pragma unroll
        for (int ot = 0; ot < 4; ot++)
#pragma unroll
          for (int r = 0; r < 4; r++) o[mi][ot][r] *= scale[mi];
    }

    // pack P^T to bf16: pk[s4][mi] IS the 16x16x16 B-frag (k=4g+j, col=r16)
    bf16x4 pk[4][2];
#pragma unroll
    for (int s4 = 0; s4 < 4; s4++)
#pragma unroll
      for (int mi = 0; mi < 2; mi++) {
        bf16x4 p;
#pragma unroll
        for (int j = 0; j < 4; j++) p[j] = (bf16)s[s4][mi][j];
        pk[s4][mi] = p;
      }

    // PV: O^T[e][q] += V^T A-frags x P^T B-frags, 4 steps of k=16
#pragma unroll
    for (int ot = 0; ot < 4; ot++) {
      const int row = ot * 16 + r16;
      const bf16x8 vf0 = *(const bf16x8*)(
          &Vs[c][row * 64 + (((2 * g + 0) ^ (r16 & 7)) * 8)]);
      const bf16x8 vf1 = *(const bf16x8*)(
          &Vs[c][row * 64 + (((2 * g + 1) ^ (r16 & 7)) * 8)]);
      const bf16x4 a0 = __builtin_shufflevector(vf0, vf0, 0, 1, 2, 3);
      const bf16x4 a1 = __builtin_shufflevector(vf0, vf0, 4, 5, 6, 7);
      const bf16x4 a2 = __builtin_shufflevector(vf1, vf1, 0, 1, 2, 3);
      const bf16x4 a3 = __builtin_shufflevector(vf1, vf1, 4, 5, 6, 7);
#pragma unroll
      for (int mi = 0; mi < 2; mi++) {
        o[mi][ot] = mfma16(a0, pk[0][mi], o[mi][ot]);
        o[mi][ot] = mfma16(a1, pk[1][mi], o[mi][ot]);
        o[mi][ot] = mfma16(a2, pk[2][mi], o[mi][ot]);
        o[mi][ot] = mfma16(a3, pk[3][mi], o[mi][ot]);
      }
    }
    __syncthreads();
  }

  asm volatile("s_nop 7\ns_nop 7");  // MFMA->VALU hazard guard before epilogue

  // epilogue: O^T col=q=r16 (same lane as l), row e = ot*16+4g+r
#pragma unroll
  for (int mi = 0; mi < 2; mi++) {
    const float li = 0.125f / lrun[mi];
    const size_t rowoff = ((size_t)b * Nq + q0 + mi * 16 + r16) * Dq + h * 64;
#pragma unroll
    for (int ot = 0; ot < 4; ot++) {
      union { bf16 h[4]; ushort4 u; } r4;
#pragma unroll
      for (int r = 0; r < 4; r++) r4.h[r] = (bf16)(o[mi][ot][r] * li);
      *(ushort4*)(att + rowoff + ot * 16 + 4 * g) = r4.u;
    }
  }
}

// ---------------- LayerNorm over D=512, one wave per row ----------------
template <bool WB>
__global__ __launch_bounds__(64) void k_ln(const float* __restrict__ in,
                                           const float* __restrict__ gamma,
                                           const float* __restrict__ beta,
                                           float* __restrict__ outf,
                                           bf16* __restrict__ outb) {
  const int row = blockIdx.x, lane = threadIdx.x;
  const float* p = in + (size_t)row * Dq + lane * 8;
  float4 a = *(const float4*)p;
  float4 c = *(const float4*)(p + 4);
  float vals[8] = {a.x, a.y, a.z, a.w, c.x, c.y, c.z, c.w};
  float s = 0.f, q = 0.f;
#pragma unroll
  for (int j = 0; j < 8; j++) { s += vals[j]; q += vals[j] * vals[j]; }
#pragma unroll
  for (int off = 1; off < 64; off <<= 1) {
    s += __shfl_xor(s, off);
    q += __shfl_xor(q, off);
  }
  float mean = s * (1.f / Dq);
  float var = q * (1.f / Dq) - mean * mean;
  float rstd = rsqrtf(var + 1e-5f);
  float of[8];
#pragma unroll
  for (int j = 0; j < 8; j++) {
    int col = lane * 8 + j;
    of[j] = (vals[j] - mean) * rstd * gamma[col] + beta[col];
  }
  float4* op = (float4*)(outf + (size_t)row * Dq + lane * 8);
  op[0] = make_float4(of[0], of[1], of[2], of[3]);
  op[1] = make_float4(of[4], of[5], of[6], of[7]);
  if (WB) {
    union { bf16 h[8]; ushort4 u[2]; } rr;
#pragma unroll
    for (int j = 0; j < 8; j++) rr.h[j] = (bf16)of[j];
    ushort4* ob = (ushort4*)(outb + (size_t)row * Dq + lane * 8);
    ob[0] = rr.u[0];
    ob[1] = rr.u[1];
  }
}

extern "C" void kernel_launch(void* const* d_in, const int* in_sizes, int n_in,
                              void* d_out, int out_size, void* d_ws, size_t ws_size,
                              hipStream_t stream) {
  const float* x      = (const float*)d_in[0];
  const float* w_qkv  = (const float*)d_in[1];
  const float* b_qkv  = (const float*)d_in[2];
  const float* w_proj = (const float*)d_in[3];
  const float* b_proj = (const float*)d_in[4];
  const float* ln1_g  = (const float*)d_in[5];
  const float* ln1_b  = (const float*)d_in[6];
  const float* w1     = (const float*)d_in[7];
  const float* b1     = (const float*)d_in[8];
  const float* w2     = (const float*)d_in[9];
  const float* b2     = (const float*)d_in[10];
  const float* ln2_g  = (const float*)d_in[11];
  const float* ln2_b  = (const float*)d_in[12];
  float* out = (float*)d_out;

  const int M = Bq * Nq;  // 8192 rows

  char* p = (char*)d_ws;
  auto alloc = [&](size_t bytes) -> void* {
    char* r = p;
    p += (bytes + 255) & ~(size_t)255;
    return (void*)r;
  };
  bf16* xb     = (bf16*)alloc((size_t)M * Dq * 2);        // x bf16; later reused as att
  bf16* qkvb   = (bf16*)alloc((size_t)M * 3 * Dq * 2);
  bf16* wqkvT  = (bf16*)alloc((size_t)3 * Dq * Dq * 2);
  bf16* wprojT = (bf16*)alloc((size_t)Dq * Dq * 2);
  bf16* w1T    = (bf16*)alloc((size_t)Hq * Dq * 2);
  bf16* w2T    = (bf16*)alloc((size_t)Dq * Hq * 2);
  float* y1    = (float*)alloc((size_t)M * Dq * 4);       // also y2
  float* x1f   = (float*)alloc((size_t)M * Dq * 4);
  bf16* x1b    = (bf16*)alloc((size_t)M * Dq * 2);
  bf16* hb     = (bf16*)alloc((size_t)M * Hq * 2);
  bf16* attb   = xb;   // alias: xb consumed by qkv GEMM before attention writes
  bf16* vtb    = hb;   // alias: hb written by ffn1 only after attention is done

  dim3 tb(32, 8);
  k_cvt_bf16<<<(M * Dq / 4 + 255) / 256, 256, 0, stream>>>(x, xb, M * Dq);
  k_transpose_cvt<<<dim3((3 * Dq) / 32, Dq / 32), tb, 0, stream>>>(w_qkv, wqkvT, Dq, 3 * Dq);
  k_transpose_cvt<<<dim3(Dq / 32, Dq / 32), tb, 0, stream>>>(w_proj, wprojT, Dq, Dq);
  k_transpose_cvt<<<dim3(Hq / 32, Dq / 32), tb, 0, stream>>>(w1, w1T, Dq, Hq);
  k_transpose_cvt<<<dim3(Dq / 32, Hq / 32), tb, 0, stream>>>(w2, w2T, Hq, Dq);

  // qkv = x @ w_qkv + b_qkv  (Q,K -> qkvb natural; V -> vtb transposed+interleaved)
  k_gemm<false, false, true, true><<<dim3((3 * Dq) / 128, M / 128), 256, 0, stream>>>(
      xb, wqkvT, b_qkv, nullptr, qkvb, vtb, M, 3 * Dq, Dq);
  // attention (bh on grid-x: all q-tiles of one (b,h) share an XCD L2)
  k_attn<<<dim3(Bq * HEADS, Nq / 128), 256, 0, stream>>>(qkvb, vtb, attb);
  // y1 = att @ w_proj + b_proj + x
  k_gemm<false, true, false, false><<<dim3(Dq / 128, M / 128), 256, 0, stream>>>(
      attb, wprojT, b_proj, x, y1, nullptr, M, Dq, Dq);
  // x1 = LN1(y1) -> fp32 + bf16
  k_ln<true><<<M, 64, 0, stream>>>(y1, ln1_g, ln1_b, x1f, x1b);
  // h = gelu(x1 @ w1 + b1)
  k_gemm<true, false, true, false><<<dim3(Hq / 128, M / 128), 256, 0, stream>>>(
      x1b, w1T, b1, nullptr, hb, nullptr, M, Hq, Dq);
  // y2 = h @ w2 + b2 + x1
  k_gemm<false, true, false, false><<<dim3(Dq / 128, M / 128), 256, 0, stream>>>(
      hb, w2T, b2, x1f, y1, nullptr, M, Dq, Hq);
  // out = LN2(y2)
  k_ln<false><<<M, 64, 0, stream>>>(y1, ln2_g, ln2_b, out, nullptr);
}

// Round 7
// 223.484 us; speedup vs baseline: 1.6897x; 1.0002x over previous
//
#include <hip/hip_runtime.h>

#define HEADS 8
#define Bq 4
#define Nq 2048
#define Dq 512
#define Hq 2048

typedef __bf16 bf16;
typedef __bf16 bf16x8 __attribute__((ext_vector_type(8)));
typedef __bf16 bf16x4 __attribute__((ext_vector_type(4)));
typedef short short4v __attribute__((ext_vector_type(4)));
typedef float f32x4 __attribute__((ext_vector_type(4)));

__device__ __forceinline__ void gload16(const bf16* g, bf16* s) {
  __builtin_amdgcn_global_load_lds(
      (const __attribute__((address_space(1))) void*)g,
      (__attribute__((address_space(3))) void*)s, 16, 0, 0);
}

// 16x16x16 bf16 MFMA (legacy shape; A/B = 4 bf16 = 2 VGPR, k = 4g..4g+3 per lane)
__device__ __forceinline__ f32x4 mfma16(bf16x4 a, bf16x4 b, f32x4 c) {
#if __has_builtin(__builtin_amdgcn_mfma_f32_16x16x16bf16_1k)
  return __builtin_amdgcn_mfma_f32_16x16x16bf16_1k(
      __builtin_bit_cast(short4v, a), __builtin_bit_cast(short4v, b), c, 0, 0, 0);
#else
  f32x4 d = c;
  asm("v_mfma_f32_16x16x16_bf16 %0, %1, %2, %0" : "+v"(d) : "v"(a), "v"(b));
  return d;
#endif
}

// ---------------- fp32 -> bf16 elementwise convert ----------------
__global__ __launch_bounds__(256) void k_cvt_bf16(const float* __restrict__ in,
                                                  bf16* __restrict__ out, int n) {
  int i = (blockIdx.x * 256 + threadIdx.x) * 4;
  if (i >= n) return;
  float4 v = *(const float4*)(in + i);
  union { bf16 h[4]; ushort4 u; } r;
  r.h[0] = (bf16)v.x; r.h[1] = (bf16)v.y; r.h[2] = (bf16)v.z; r.h[3] = (bf16)v.w;
  *(ushort4*)(out + i) = r.u;
}

// ---------------- transpose + convert: in fp32 [K][N] -> out bf16 [N][K] ----------------
__global__ __launch_bounds__(256) void k_transpose_cvt(const float* __restrict__ in,
                                                       bf16* __restrict__ out,
                                                       int K, int N) {
  __shared__ float t[32][33];
  const int n0 = blockIdx.x * 32, k0 = blockIdx.y * 32;
  const int tx = threadIdx.x, ty = threadIdx.y;
#pragma unroll
  for (int j = 0; j < 32; j += 8)
    t[ty + j][tx] = in[(size_t)(k0 + ty + j) * N + n0 + tx];
  __syncthreads();
#pragma unroll
  for (int j = 0; j < 32; j += 8)
    out[(size_t)(n0 + ty + j) * K + k0 + tx] = (bf16)t[tx][ty + j];
}

// ---------------- GEMM: C[M][N] = A[M][K](bf16) * BT[N][K]^T + bias ----------------
// BM x 128 tile, BK=32, 4 waves (2x2). global_load_lds width-16 staging,
// double-buffered, 32/24 KB LDS (4-5 blocks/CU). With BK=32 the 64-B LDS row
// stride makes both staging writes and b128 frag reads naturally conflict-free
// ((row&1) selects the 16-bank half) -> no swizzle needed.
template <int BM, bool GELU, bool RESID, bool STORE_BF16>
__global__ __launch_bounds__(256) void k_gemm(const bf16* __restrict__ A,
                                              const bf16* __restrict__ BT,
                                              const float* __restrict__ bias,
                                              const float* __restrict__ resid,
                                              void* __restrict__ Cout,
                                              int M, int N, int K) {
  constexpr int MI = BM / 32;   // M-frags per wave
  constexpr int AI = BM / 64;   // A staging instrs per wave
  __shared__ bf16 As[2][BM * 32];
  __shared__ bf16 Bs[2][128 * 32];
  const int m0 = blockIdx.y * BM, n0 = blockIdx.x * 128;
  const int tid = threadIdx.x, lane = tid & 63, wid = tid >> 6;
  const int wr = wid >> 1, wc = wid & 1;
  const int r16 = lane & 15, g = lane >> 4;
  const int srow = lane >> 2;   // 0..15 rows per staging instr
  const int sch = lane & 3;     // 16-B chunk within 64-B row

  f32x4 acc[MI][4] = {};

  const int NT = K >> 5;
  auto stage = [&](int t, int buf) {
    const int k0 = t << 5;
#pragma unroll
    for (int i = 0; i < AI; i++) {
      int rl = wid * (BM / 4) + i * 16 + srow;
      gload16(A + (size_t)(m0 + rl) * K + k0 + sch * 8,
              &As[buf][(wid * (BM / 4) + i * 16) * 32]);
    }
#pragma unroll
    for (int i = 0; i < 2; i++) {
      int rl = wid * 32 + i * 16 + srow;
      gload16(BT + (size_t)(n0 + rl) * K + k0 + sch * 8,
              &Bs[buf][(wid * 32 + i * 16) * 32]);
    }
  };

  stage(0, 0);
  __syncthreads();

  for (int t = 0; t < NT; t++) {
    const int cur = t & 1;
    if (t + 1 < NT) stage(t + 1, cur ^ 1);
    bf16x8 af[MI], bfr[4];
#pragma unroll
    for (int mi = 0; mi < MI; mi++)
      af[mi] = *(const bf16x8*)(&As[cur][(wr * (BM / 2) + mi * 16 + r16) * 32 + g * 8]);
#pragma unroll
    for (int ni = 0; ni < 4; ni++)
      bfr[ni] = *(const bf16x8*)(&Bs[cur][(wc * 64 + ni * 16 + r16) * 32 + g * 8]);
#pragma unroll
    for (int mi = 0; mi < MI; mi++)
#pragma unroll
      for (int ni = 0; ni < 4; ni++)
        acc[mi][ni] = __builtin_amdgcn_mfma_f32_16x16x32_bf16(af[mi], bfr[ni],
                                                              acc[mi][ni], 0, 0, 0);
    __syncthreads();
  }

#pragma unroll
  for (int mi = 0; mi < MI; mi++)
#pragma unroll
    for (int ni = 0; ni < 4; ni++) {
      int col = n0 + wc * 64 + ni * 16 + r16;
      float bv = bias[col];
#pragma unroll
      for (int r = 0; r < 4; r++) {
        int row = m0 + wr * (BM / 2) + mi * 16 + 4 * g + r;
        float v = acc[mi][ni][r] + bv;
        if (GELU) v = 0.5f * v * (1.f + erff(v * 0.70710678118654752f));
        if (RESID) v += resid[(size_t)row * N + col];
        if (STORE_BF16) ((bf16*)Cout)[(size_t)row * N + col] = (bf16)v;
        else            ((float*)Cout)[(size_t)row * N + col] = v;
      }
    }
}

// ---------------- V transpose+interleave: qkvb V-cols -> vt[B*H][64][Nq] ----------------
// vt[(b*8+h)*64+e][kv0 + p] = V[kv0 + kvmap(p)][h*64+e], kvmap(p)=16*((p>>2)&3)+4*(p>>4)+(p&3).
// Coalesced 128-B reads (staged via LDS, stride 66 = conflict-free transpose read)
// and coalesced 128-B writes.
__global__ __launch_bounds__(256) void k_vtrans(const bf16* __restrict__ qkv,
                                                bf16* __restrict__ vt) {
  __shared__ bf16 T[64 * 66];
  const int kvb = blockIdx.x, bh = blockIdx.y;
  const int b = bh >> 3, h = bh & 7;
  const int tid = threadIdx.x, lane = tid & 63, w = tid >> 6;
  const bf16* src = qkv + ((size_t)b * Nq + kvb * 64) * (3 * Dq) + 2 * Dq + h * 64;
#pragma unroll
  for (int i = 0; i < 2; i++) {
    int u = tid + i * 256;
    int r = u >> 3, ch = u & 7;
    *(int4*)(&T[r * 66 + ch * 8]) = *(const int4*)(src + (size_t)r * (3 * Dq) + ch * 8);
  }
  __syncthreads();
  const int kvm = 16 * ((lane >> 2) & 3) + 4 * (lane >> 4) + (lane & 3);
  bf16* dst = vt + (size_t)bh * 64 * Nq + kvb * 64 + lane;
#pragma unroll
  for (int it = 0; it < 16; it++) {
    int e = w * 16 + it;
    dst[(size_t)e * Nq] = T[kvm * 66 + e];
  }
}

// ---------------- flash attention: O^T = V^T P^T, zero-shuffle PV ----------------
// grid (B*H, Nq/128), 256 thr = 4 waves, 32 q-rows/wave, KVBLK=64.
// S^T = mfma_16x16x32(A=K, B=Q): lane holds P^T[kv=4g+reg][q=r16].
// PV = mfma_16x16x16(A=V^T frag, B=P^T-from-regs): S^T C-layout == B-frag layout.
__global__ __launch_bounds__(256) void k_attn(const bf16* __restrict__ qkv,
                                              const bf16* __restrict__ vt,
                                              bf16* __restrict__ att) {
  __shared__ bf16 Ks[2][64 * 64];
  __shared__ bf16 Vs[2][64 * 64];
  const int qt = blockIdx.y, b = blockIdx.x >> 3, h = blockIdx.x & 7;
  const int tid = threadIdx.x, lane = tid & 63, wid = tid >> 6;
  const int r16 = lane & 15, g = lane >> 4;
  const size_t base = (size_t)b * Nq * (3 * Dq);
  const bf16* qp = qkv + base + h * 64;
  const bf16* kp = qkv + base + Dq + h * 64;
  const bf16* vtp = vt + (size_t)(b * HEADS + h) * 64 * Nq;
  const int q0 = qt * 128 + wid * 32;

  bf16x8 qf[2][2];
#pragma unroll
  for (int mi = 0; mi < 2; mi++)
#pragma unroll
    for (int kk = 0; kk < 2; kk++)
      qf[mi][kk] = *(const bf16x8*)(qp + (size_t)(q0 + mi * 16 + r16) * (3 * Dq) +
                                    kk * 32 + g * 8);

  const int srow = lane >> 3;
  const int sch = (lane & 7) ^ srow;

  f32x4 o[2][4] = {};
  float mrun[2] = {-INFINITY, -INFINITY}, lrun[2] = {0.f, 0.f};

#pragma unroll
  for (int i = 0; i < 2; i++) {
    int br = (wid * 2 + i) * 8;
    gload16(kp + (size_t)(br + srow) * (3 * Dq) + sch * 8, &Ks[0][br * 64]);
    gload16(vtp + (size_t)(br + srow) * Nq + sch * 8, &Vs[0][br * 64]);
  }
  __syncthreads();

  const int NTILES = Nq / 64;
  for (int t = 0; t < NTILES; t++) {
    const int c = t & 1;
    if (t + 1 < NTILES) {
      const int kv1 = (t + 1) * 64;
#pragma unroll
      for (int i = 0; i < 2; i++) {
        int br = (wid * 2 + i) * 8;
        gload16(kp + (size_t)(kv1 + br + srow) * (3 * Dq) + sch * 8,
                &Ks[c ^ 1][br * 64]);
        gload16(vtp + (size_t)(br + srow) * Nq + kv1 + sch * 8, &Vs[c ^ 1][br * 64]);
      }
    }

    // S^T[kv][q]: s[nt][mi]
    f32x4 s[4][2] = {};
#pragma unroll
    for (int kk = 0; kk < 2; kk++)
#pragma unroll
      for (int nt = 0; nt < 4; nt++) {
        const bf16x8 kf = *(const bf16x8*)(
            &Ks[c][(nt * 16 + r16) * 64 + (((4 * kk + g) ^ (r16 & 7)) * 8)]);
#pragma unroll
        for (int mi = 0; mi < 2; mi++)
          s[nt][mi] = __builtin_amdgcn_mfma_f32_16x16x32_bf16(kf, qf[mi][kk],
                                                              s[nt][mi], 0, 0, 0);
      }

    // online softmax with defer-max (THR=8); stats live on lane's q=r16
    float scale[2];
    bool need[2];
#pragma unroll
    for (int mi = 0; mi < 2; mi++) {
      float mx = s[0][mi][0];
#pragma unroll
      for (int nt = 0; nt < 4; nt++)
#pragma unroll
        for (int r = 0; r < 4; r++) mx = fmaxf(mx, s[nt][mi][r]);
      mx = fmaxf(mx, __shfl_xor(mx, 16));
      mx = fmaxf(mx, __shfl_xor(mx, 32));
      const float mold = mrun[mi];
      need[mi] = (mx > mold + 8.f);
      const float mn = need[mi] ? mx : mold;
      mrun[mi] = mn;
      float rs = 0.f;
#pragma unroll
      for (int nt = 0; nt < 4; nt++)
#pragma unroll
        for (int r = 0; r < 4; r++) {
          float pv = __expf(s[nt][mi][r] - mn);
          s[nt][mi][r] = pv;
          rs += pv;
        }
      rs += __shfl_xor(rs, 16);
      rs += __shfl_xor(rs, 32);
      scale[mi] = need[mi] ? __expf(mold - mn) : 1.f;
      lrun[mi] = need[mi] ? lrun[mi] * scale[mi] + rs : lrun[mi] + rs;
    }
    if (__any(need[0] || need[1])) {
#pragma unroll
      for (int mi = 0; mi < 2; mi++)
#pragma unroll
        for (int ot = 0; ot < 4; ot++)
#pragma unroll
          for (int r = 0; r < 4; r++) o[mi][ot][r] *= scale[mi];
    }

    // pack P^T to bf16: pk[s4][mi] IS the 16x16x16 B-frag (k=4g+j, col=r16)
    bf16x4 pk[4][2];
#pragma unroll
    for (int s4 = 0; s4 < 4; s4++)
#pragma unroll
      for (int mi = 0; mi < 2; mi++) {
        bf16x4 p;
#pragma unroll
        for (int j = 0; j < 4; j++) p[j] = (bf16)s[s4][mi][j];
        pk[s4][mi] = p;
      }

    // PV: O^T[e][q] += V^T A-frags x P^T B-frags, 4 steps of k=16
#pragma unroll
    for (int ot = 0; ot < 4; ot++) {
      const int row = ot * 16 + r16;
      const bf16x8 vf0 = *(const bf16x8*)(
          &Vs[c][row * 64 + (((2 * g + 0) ^ (r16 & 7)) * 8)]);
      const bf16x8 vf1 = *(const bf16x8*)(
          &Vs[c][row * 64 + (((2 * g + 1) ^ (r16 & 7)) * 8)]);
      const bf16x4 a0 = __builtin_shufflevector(vf0, vf0, 0, 1, 2, 3);
      const bf16x4 a1 = __builtin_shufflevector(vf0, vf0, 4, 5, 6, 7);
      const bf16x4 a2 = __builtin_shufflevector(vf1, vf1, 0, 1, 2, 3);
      const bf16x4 a3 = __builtin_shufflevector(vf1, vf1, 4, 5, 6, 7);
#pragma unroll
      for (int mi = 0; mi < 2; mi++) {
        o[mi][ot] = mfma16(a0, pk[0][mi], o[mi][ot]);
        o[mi][ot] = mfma16(a1, pk[1][mi], o[mi][ot]);
        o[mi][ot] = mfma16(a2, pk[2][mi], o[mi][ot]);
        o[mi][ot] = mfma16(a3, pk[3][mi], o[mi][ot]);
      }
    }
    __syncthreads();
  }

  asm volatile("s_nop 7\ns_nop 7");  // MFMA->VALU hazard guard before epilogue

  // epilogue: O^T col=q=r16 (same lane as l), row e = ot*16+4g+r
#pragma unroll
  for (int mi = 0; mi < 2; mi++) {
    const float li = 0.125f / lrun[mi];
    const size_t rowoff = ((size_t)b * Nq + q0 + mi * 16 + r16) * Dq + h * 64;
#pragma unroll
    for (int ot = 0; ot < 4; ot++) {
      union { bf16 h[4]; ushort4 u; } r4;
#pragma unroll
      for (int r = 0; r < 4; r++) r4.h[r] = (bf16)(o[mi][ot][r] * li);
      *(ushort4*)(att + rowoff + ot * 16 + 4 * g) = r4.u;
    }
  }
}

// ---------------- LayerNorm over D=512, one wave per row ----------------
template <bool WB>
__global__ __launch_bounds__(64) void k_ln(const float* __restrict__ in,
                                           const float* __restrict__ gamma,
                                           const float* __restrict__ beta,
                                           float* __restrict__ outf,
                                           bf16* __restrict__ outb) {
  const int row = blockIdx.x, lane = threadIdx.x;
  const float* p = in + (size_t)row * Dq + lane * 8;
  float4 a = *(const float4*)p;
  float4 c = *(const float4*)(p + 4);
  float vals[8] = {a.x, a.y, a.z, a.w, c.x, c.y, c.z, c.w};
  float s = 0.f, q = 0.f;
#pragma unroll
  for (int j = 0; j < 8; j++) { s += vals[j]; q += vals[j] * vals[j]; }
#pragma unroll
  for (int off = 1; off < 64; off <<= 1) {
    s += __shfl_xor(s, off);
    q += __shfl_xor(q, off);
  }
  float mean = s * (1.f / Dq);
  float var = q * (1.f / Dq) - mean * mean;
  float rstd = rsqrtf(var + 1e-5f);
  float of[8];
#pragma unroll
  for (int j = 0; j < 8; j++) {
    int col = lane * 8 + j;
    of[j] = (vals[j] - mean) * rstd * gamma[col] + beta[col];
  }
  float4* op = (float4*)(outf + (size_t)row * Dq + lane * 8);
  op[0] = make_float4(of[0], of[1], of[2], of[3]);
  op[1] = make_float4(of[4], of[5], of[6], of[7]);
  if (WB) {
    union { bf16 h[8]; ushort4 u[2]; } rr;
#pragma unroll
    for (int j = 0; j < 8; j++) rr.h[j] = (bf16)of[j];
    ushort4* ob = (ushort4*)(outb + (size_t)row * Dq + lane * 8);
    ob[0] = rr.u[0];
    ob[1] = rr.u[1];
  }
}

extern "C" void kernel_launch(void* const* d_in, const int* in_sizes, int n_in,
                              void* d_out, int out_size, void* d_ws, size_t ws_size,
                              hipStream_t stream) {
  const float* x      = (const float*)d_in[0];
  const float* w_qkv  = (const float*)d_in[1];
  const float* b_qkv  = (const float*)d_in[2];
  const float* w_proj = (const float*)d_in[3];
  const float* b_proj = (const float*)d_in[4];
  const float* ln1_g  = (const float*)d_in[5];
  const float* ln1_b  = (const float*)d_in[6];
  const float* w1     = (const float*)d_in[7];
  const float* b1     = (const float*)d_in[8];
  const float* w2     = (const float*)d_in[9];
  const float* b2     = (const float*)d_in[10];
  const float* ln2_g  = (const float*)d_in[11];
  const float* ln2_b  = (const float*)d_in[12];
  float* out = (float*)d_out;

  const int M = Bq * Nq;  // 8192 rows

  char* p = (char*)d_ws;
  auto alloc = [&](size_t bytes) -> void* {
    char* r = p;
    p += (bytes + 255) & ~(size_t)255;
    return (void*)r;
  };
  bf16* xb     = (bf16*)alloc((size_t)M * Dq * 2);        // x bf16; later reused as att
  bf16* qkvb   = (bf16*)alloc((size_t)M * 3 * Dq * 2);
  bf16* wqkvT  = (bf16*)alloc((size_t)3 * Dq * Dq * 2);
  bf16* wprojT = (bf16*)alloc((size_t)Dq * Dq * 2);
  bf16* w1T    = (bf16*)alloc((size_t)Hq * Dq * 2);
  bf16* w2T    = (bf16*)alloc((size_t)Dq * Hq * 2);
  float* y1    = (float*)alloc((size_t)M * Dq * 4);       // also y2
  float* x1f   = (float*)alloc((size_t)M * Dq * 4);
  bf16* x1b    = (bf16*)alloc((size_t)M * Dq * 2);
  bf16* hb     = (bf16*)alloc((size_t)M * Hq * 2);
  bf16* attb   = xb;   // alias: xb consumed by qkv GEMM before attention writes
  bf16* vtb    = hb;   // alias: hb written by ffn1 only after attention is done

  dim3 tb(32, 8);
  k_cvt_bf16<<<(M * Dq / 4 + 255) / 256, 256, 0, stream>>>(x, xb, M * Dq);
  k_transpose_cvt<<<dim3((3 * Dq) / 32, Dq / 32), tb, 0, stream>>>(w_qkv, wqkvT, Dq, 3 * Dq);
  k_transpose_cvt<<<dim3(Dq / 32, Dq / 32), tb, 0, stream>>>(w_proj, wprojT, Dq, Dq);
  k_transpose_cvt<<<dim3(Hq / 32, Dq / 32), tb, 0, stream>>>(w1, w1T, Dq, Hq);
  k_transpose_cvt<<<dim3(Dq / 32, Hq / 32), tb, 0, stream>>>(w2, w2T, Hq, Dq);

  // qkv = x @ w_qkv + b_qkv  (all 1536 cols coalesced into qkvb)
  k_gemm<128, false, false, true><<<dim3((3 * Dq) / 128, M / 128), 256, 0, stream>>>(
      xb, wqkvT, b_qkv, nullptr, qkvb, M, 3 * Dq, Dq);
  // vt = transpose+interleave of V part
  k_vtrans<<<dim3(Nq / 64, Bq * HEADS), 256, 0, stream>>>(qkvb, vtb);
  // attention
  k_attn<<<dim3(Bq * HEADS, Nq / 128), 256, 0, stream>>>(qkvb, vtb, attb);
  // y1 = att @ w_proj + b_proj + x   (BM=64: grid 512, 2 blocks/CU)
  k_gemm<64, false, true, false><<<dim3(Dq / 128, M / 64), 256, 0, stream>>>(
      attb, wprojT, b_proj, x, y1, M, Dq, Dq);
  // x1 = LN1(y1) -> fp32 + bf16
  k_ln<true><<<M, 64, 0, stream>>>(y1, ln1_g, ln1_b, x1f, x1b);
  // h = gelu(x1 @ w1 + b1)
  k_gemm<128, true, false, true><<<dim3(Hq / 128, M / 128), 256, 0, stream>>>(
      x1b, w1T, b1, nullptr, hb, M, Hq, Dq);
  // y2 = h @ w2 + b2 + x1   (BM=64)
  k_gemm<64, false, true, false><<<dim3(Dq / 128, M / 64), 256, 0, stream>>>(
      hb, w2T, b2, x1f, y1, M, Dq, Hq);
  // out = LN2(y2)
  k_ln<false><<<M, 64, 0, stream>>>(y1, ln2_g, ln2_b, out, nullptr);
}

// Round 8
// 199.676 us; speedup vs baseline: 1.8912x; 1.1192x over previous
//
#include <hip/hip_runtime.h>

#define HEADS 8
#define Bq 4
#define Nq 2048
#define Dq 512
#define Hq 2048

typedef __bf16 bf16;
typedef __bf16 bf16x8 __attribute__((ext_vector_type(8)));
typedef __bf16 bf16x4 __attribute__((ext_vector_type(4)));
typedef short short4v __attribute__((ext_vector_type(4)));
typedef float f32x4 __attribute__((ext_vector_type(4)));

__device__ __forceinline__ void gload16(const bf16* g, bf16* s) {
  __builtin_amdgcn_global_load_lds(
      (const __attribute__((address_space(1))) void*)g,
      (__attribute__((address_space(3))) void*)s, 16, 0, 0);
}

// 16x16x16 bf16 MFMA (legacy shape; A/B = 4 bf16 = 2 VGPR, k = 4g..4g+3 per lane)
__device__ __forceinline__ f32x4 mfma16(bf16x4 a, bf16x4 b, f32x4 c) {
#if __has_builtin(__builtin_amdgcn_mfma_f32_16x16x16bf16_1k)
  return __builtin_amdgcn_mfma_f32_16x16x16bf16_1k(
      __builtin_bit_cast(short4v, a), __builtin_bit_cast(short4v, b), c, 0, 0, 0);
#else
  f32x4 d = c;
  asm("v_mfma_f32_16x16x16_bf16 %0, %1, %2, %0" : "+v"(d) : "v"(a), "v"(b));
  return d;
#endif
}

// ---------------- fp32 -> bf16 elementwise convert ----------------
__global__ __launch_bounds__(256) void k_cvt_bf16(const float* __restrict__ in,
                                                  bf16* __restrict__ out, int n) {
  int i = (blockIdx.x * 256 + threadIdx.x) * 4;
  if (i >= n) return;
  float4 v = *(const float4*)(in + i);
  union { bf16 h[4]; ushort4 u; } r;
  r.h[0] = (bf16)v.x; r.h[1] = (bf16)v.y; r.h[2] = (bf16)v.z; r.h[3] = (bf16)v.w;
  *(ushort4*)(out + i) = r.u;
}

// ---------------- transpose + convert: in fp32 [K][N] -> out bf16 [N][K] ----------------
__global__ __launch_bounds__(256) void k_transpose_cvt(const float* __restrict__ in,
                                                       bf16* __restrict__ out,
                                                       int K, int N) {
  __shared__ float t[32][33];
  const int n0 = blockIdx.x * 32, k0 = blockIdx.y * 32;
  const int tx = threadIdx.x, ty = threadIdx.y;
#pragma unroll
  for (int j = 0; j < 32; j += 8)
    t[ty + j][tx] = in[(size_t)(k0 + ty + j) * N + n0 + tx];
  __syncthreads();
#pragma unroll
  for (int j = 0; j < 32; j += 8)
    out[(size_t)(n0 + ty + j) * K + k0 + tx] = (bf16)t[tx][ty + j];
}

// ---------------- GEMM: C[M][N] = A[M][K](bf16) * BT[N][K]^T + bias ----------------
// BM x 128 tile, BK=64, 512 threads = 8 waves (2 wr x 4 wc). global_load_lds
// width-16 staging (linear dest + inverse-XOR source), double-buffered,
// XOR-swizzled b128 frag reads (round-6-proven 0-conflict). Epilogue bounces
// the C-tile through LDS for 16-B/lane coalesced stores (kills write-allocate
// RMW overfetch seen as FETCH 35MB vs 10MB ideal).
template <int BM, bool GELU, bool RESID, bool STORE_BF16>
__global__ __launch_bounds__(512, 4) void k_gemm(const bf16* __restrict__ A,
                                                 const bf16* __restrict__ BT,
                                                 const float* __restrict__ bias,
                                                 const float* __restrict__ resid,
                                                 void* __restrict__ Cout,
                                                 int M, int N, int K) {
  constexpr int MI = BM / 32;          // M-frags per wave (wave M-span = BM/2)
  constexpr int AROUNDS = BM / 64;     // 512-thr staging rounds for A
  constexpr size_t MAIN = (size_t)2 * (BM + 128) * 64 * 2;
  constexpr size_t CST = (size_t)BM * 136 * (STORE_BF16 ? 2 : 4);
  constexpr size_t SMEM = MAIN > CST ? MAIN : CST;
  __shared__ __align__(16) char smem[SMEM];
  bf16* Asb = (bf16*)smem;                     // [2][BM*64]
  bf16* Bsb = Asb + 2 * BM * 64;               // [2][128*64]

  const int m0 = blockIdx.y * BM, n0 = blockIdx.x * 128;
  const int tid = threadIdx.x, lane = tid & 63, wid = tid >> 6;
  const int wr = wid >> 2, wc = wid & 3;
  const int r16 = lane & 15, g = lane >> 4;
  const int lrow = lane >> 3;                  // 0..7 rows within a gload round
  const int sch = (lane & 7) ^ lrow;           // inverse-swizzled source chunk

  f32x4 acc[MI][2] = {};

  const int NT = K >> 6;
  auto stage = [&](int t, int buf) {
    const int k0 = t << 6;
#pragma unroll
    for (int i = 0; i < AROUNDS; i++) {
      int row = i * 64 + wid * 8 + lrow;
      gload16(A + (size_t)(m0 + row) * K + k0 + sch * 8,
              Asb + buf * BM * 64 + (i * 64 + wid * 8) * 64);
    }
#pragma unroll
    for (int i = 0; i < 2; i++) {
      int row = i * 64 + wid * 8 + lrow;
      gload16(BT + (size_t)(n0 + row) * K + k0 + sch * 8,
              Bsb + buf * 128 * 64 + (i * 64 + wid * 8) * 64);
    }
  };

  stage(0, 0);
  __syncthreads();

  for (int t = 0; t < NT; t++) {
    const int cur = t & 1;
    if (t + 1 < NT) stage(t + 1, cur ^ 1);
    const bf16* Ab = Asb + cur * BM * 64;
    const bf16* Bb = Bsb + cur * 128 * 64;
#pragma unroll
    for (int kk = 0; kk < 2; kk++) {
      bf16x8 af[MI], bfr[2];
#pragma unroll
      for (int mi = 0; mi < MI; mi++)
        af[mi] = *(const bf16x8*)(Ab + (wr * (BM / 2) + mi * 16 + r16) * 64 +
                                  (((kk * 4 + g) ^ (r16 & 7)) * 8));
#pragma unroll
      for (int ni = 0; ni < 2; ni++)
        bfr[ni] = *(const bf16x8*)(Bb + (wc * 32 + ni * 16 + r16) * 64 +
                                   (((kk * 4 + g) ^ (r16 & 7)) * 8));
#pragma unroll
      for (int mi = 0; mi < MI; mi++)
#pragma unroll
        for (int ni = 0; ni < 2; ni++)
          acc[mi][ni] = __builtin_amdgcn_mfma_f32_16x16x32_bf16(af[mi], bfr[ni],
                                                                acc[mi][ni], 0, 0, 0);
    }
    __syncthreads();
  }

  // ---- epilogue: acc -> LDS C-tile -> coalesced 16B stores ----
  float bv[2];
#pragma unroll
  for (int ni = 0; ni < 2; ni++) bv[ni] = bias[n0 + wc * 32 + ni * 16 + r16];

  if (STORE_BF16) {
    bf16* Cl = (bf16*)smem;
#pragma unroll
    for (int mi = 0; mi < MI; mi++)
#pragma unroll
      for (int ni = 0; ni < 2; ni++)
#pragma unroll
        for (int r = 0; r < 4; r++) {
          float v = acc[mi][ni][r] + bv[ni];
          if (GELU) v = 0.5f * v * (1.f + erff(v * 0.70710678118654752f));
          Cl[(wr * (BM / 2) + mi * 16 + 4 * g + r) * 136 + wc * 32 + ni * 16 + r16] =
              (bf16)v;
        }
    __syncthreads();
    constexpr int ROWS_PER = 512 * 8 / 128;  // 32
#pragma unroll
    for (int rr = 0; rr < BM / ROWS_PER; rr++) {
      int row = rr * ROWS_PER + (tid >> 4);
      int cc = (tid & 15) * 8;
      bf16x8 v = *(const bf16x8*)(Cl + row * 136 + cc);
      *(bf16x8*)((bf16*)Cout + (size_t)(m0 + row) * N + n0 + cc) = v;
    }
  } else {
    float* Cl = (float*)smem;
#pragma unroll
    for (int mi = 0; mi < MI; mi++)
#pragma unroll
      for (int ni = 0; ni < 2; ni++)
#pragma unroll
        for (int r = 0; r < 4; r++) {
          float v = acc[mi][ni][r] + bv[ni];
          if (GELU) v = 0.5f * v * (1.f + erff(v * 0.70710678118654752f));
          Cl[(wr * (BM / 2) + mi * 16 + 4 * g + r) * 136 + wc * 32 + ni * 16 + r16] = v;
        }
    __syncthreads();
    constexpr int ROWS_PER = 512 * 4 / 128;  // 16
#pragma unroll
    for (int rr = 0; rr < BM / ROWS_PER; rr++) {
      int row = rr * ROWS_PER + (tid >> 5);
      int cc = (tid & 31) * 4;
      f32x4 v = *(const f32x4*)(Cl + row * 136 + cc);
      if (RESID) {
        f32x4 rv = *(const f32x4*)(resid + (size_t)(m0 + row) * N + n0 + cc);
        v += rv;
      }
      *(f32x4*)((float*)Cout + (size_t)(m0 + row) * N + n0 + cc) = v;
    }
  }
}

// ---------------- V transpose+interleave: qkvb V-cols -> vt[B*H][64][Nq] ----------------
__global__ __launch_bounds__(256) void k_vtrans(const bf16* __restrict__ qkv,
                                                bf16* __restrict__ vt) {
  __shared__ bf16 T[64 * 66];
  const int kvb = blockIdx.x, bh = blockIdx.y;
  const int b = bh >> 3, h = bh & 7;
  const int tid = threadIdx.x, lane = tid & 63, w = tid >> 6;
  const bf16* src = qkv + ((size_t)b * Nq + kvb * 64) * (3 * Dq) + 2 * Dq + h * 64;
#pragma unroll
  for (int i = 0; i < 2; i++) {
    int u = tid + i * 256;
    int r = u >> 3, ch = u & 7;
    *(int4*)(&T[r * 66 + ch * 8]) = *(const int4*)(src + (size_t)r * (3 * Dq) + ch * 8);
  }
  __syncthreads();
  const int kvm = 16 * ((lane >> 2) & 3) + 4 * (lane >> 4) + (lane & 3);
  bf16* dst = vt + (size_t)bh * 64 * Nq + kvb * 64 + lane;
#pragma unroll
  for (int it = 0; it < 16; it++) {
    int e = w * 16 + it;
    dst[(size_t)e * Nq] = T[kvm * 66 + e];
  }
}

// ---------------- flash attention: O^T = V^T P^T, zero-shuffle PV ----------------
__global__ __launch_bounds__(256) void k_attn(const bf16* __restrict__ qkv,
                                              const bf16* __restrict__ vt,
                                              bf16* __restrict__ att) {
  __shared__ bf16 Ks[2][64 * 64];
  __shared__ bf16 Vs[2][64 * 64];
  const int qt = blockIdx.y, b = blockIdx.x >> 3, h = blockIdx.x & 7;
  const int tid = threadIdx.x, lane = tid & 63, wid = tid >> 6;
  const int r16 = lane & 15, g = lane >> 4;
  const size_t base = (size_t)b * Nq * (3 * Dq);
  const bf16* qp = qkv + base + h * 64;
  const bf16* kp = qkv + base + Dq + h * 64;
  const bf16* vtp = vt + (size_t)(b * HEADS + h) * 64 * Nq;
  const int q0 = qt * 128 + wid * 32;

  bf16x8 qf[2][2];
#pragma unroll
  for (int mi = 0; mi < 2; mi++)
#pragma unroll
    for (int kk = 0; kk < 2; kk++)
      qf[mi][kk] = *(const bf16x8*)(qp + (size_t)(q0 + mi * 16 + r16) * (3 * Dq) +
                                    kk * 32 + g * 8);

  const int srow = lane >> 3;
  const int sch = (lane & 7) ^ srow;

  f32x4 o[2][4] = {};
  float mrun[2] = {-INFINITY, -INFINITY}, lrun[2] = {0.f, 0.f};

#pragma unroll
  for (int i = 0; i < 2; i++) {
    int br = (wid * 2 + i) * 8;
    gload16(kp + (size_t)(br + srow) * (3 * Dq) + sch * 8, &Ks[0][br * 64]);
    gload16(vtp + (size_t)(br + srow) * Nq + sch * 8, &Vs[0][br * 64]);
  }
  __syncthreads();

  const int NTILES = Nq / 64;
  for (int t = 0; t < NTILES; t++) {
    const int c = t & 1;
    if (t + 1 < NTILES) {
      const int kv1 = (t + 1) * 64;
#pragma unroll
      for (int i = 0; i < 2; i++) {
        int br = (wid * 2 + i) * 8;
        gload16(kp + (size_t)(kv1 + br + srow) * (3 * Dq) + sch * 8,
                &Ks[c ^ 1][br * 64]);
        gload16(vtp + (size_t)(br + srow) * Nq + kv1 + sch * 8, &Vs[c ^ 1][br * 64]);
      }
    }

    f32x4 s[4][2] = {};
#pragma unroll
    for (int kk = 0; kk < 2; kk++)
#pragma unroll
      for (int nt = 0; nt < 4; nt++) {
        const bf16x8 kf = *(const bf16x8*)(
            &Ks[c][(nt * 16 + r16) * 64 + (((4 * kk + g) ^ (r16 & 7)) * 8)]);
#pragma unroll
        for (int mi = 0; mi < 2; mi++)
          s[nt][mi] = __builtin_amdgcn_mfma_f32_16x16x32_bf16(kf, qf[mi][kk],
                                                              s[nt][mi], 0, 0, 0);
      }

    float scale[2];
    bool need[2];
#pragma unroll
    for (int mi = 0; mi < 2; mi++) {
      float mx = s[0][mi][0];
#pragma unroll
      for (int nt = 0; nt < 4; nt++)
#pragma unroll
        for (int r = 0; r < 4; r++) mx = fmaxf(mx, s[nt][mi][r]);
      mx = fmaxf(mx, __shfl_xor(mx, 16));
      mx = fmaxf(mx, __shfl_xor(mx, 32));
      const float mold = mrun[mi];
      need[mi] = (mx > mold + 8.f);
      const float mn = need[mi] ? mx : mold;
      mrun[mi] = mn;
      float rs = 0.f;
#pragma unroll
      for (int nt = 0; nt < 4; nt++)
#pragma unroll
        for (int r = 0; r < 4; r++) {
          float pv = __expf(s[nt][mi][r] - mn);
          s[nt][mi][r] = pv;
          rs += pv;
        }
      rs += __shfl_xor(rs, 16);
      rs += __shfl_xor(rs, 32);
      scale[mi] = need[mi] ? __expf(mold - mn) : 1.f;
      lrun[mi] = need[mi] ? lrun[mi] * scale[mi] + rs : lrun[mi] + rs;
    }
    if (__any(need[0] || need[1])) {
#pragma unroll
      for (int mi = 0; mi < 2; mi++)
#pragma unroll
        for (int ot = 0; ot < 4; ot++)
#pragma unroll
          for (int r = 0; r < 4; r++) o[mi][ot][r] *= scale[mi];
    }

    bf16x4 pk[4][2];
#pragma unroll
    for (int s4 = 0; s4 < 4; s4++)
#pragma unroll
      for (int mi = 0; mi < 2; mi++) {
        bf16x4 p;
#pragma unroll
        for (int j = 0; j < 4; j++) p[j] = (bf16)s[s4][mi][j];
        pk[s4][mi] = p;
      }

#pragma unroll
    for (int ot = 0; ot < 4; ot++) {
      const int row = ot * 16 + r16;
      const bf16x8 vf0 = *(const bf16x8*)(
          &Vs[c][row * 64 + (((2 * g + 0) ^ (r16 & 7)) * 8)]);
      const bf16x8 vf1 = *(const bf16x8*)(
          &Vs[c][row * 64 + (((2 * g + 1) ^ (r16 & 7)) * 8)]);
      const bf16x4 a0 = __builtin_shufflevector(vf0, vf0, 0, 1, 2, 3);
      const bf16x4 a1 = __builtin_shufflevector(vf0, vf0, 4, 5, 6, 7);
      const bf16x4 a2 = __builtin_shufflevector(vf1, vf1, 0, 1, 2, 3);
      const bf16x4 a3 = __builtin_shufflevector(vf1, vf1, 4, 5, 6, 7);
#pragma unroll
      for (int mi = 0; mi < 2; mi++) {
        o[mi][ot] = mfma16(a0, pk[0][mi], o[mi][ot]);
        o[mi][ot] = mfma16(a1, pk[1][mi], o[mi][ot]);
        o[mi][ot] = mfma16(a2, pk[2][mi], o[mi][ot]);
        o[mi][ot] = mfma16(a3, pk[3][mi], o[mi][ot]);
      }
    }
    __syncthreads();
  }

  asm volatile("s_nop 7\ns_nop 7");

#pragma unroll
  for (int mi = 0; mi < 2; mi++) {
    const float li = 0.125f / lrun[mi];
    const size_t rowoff = ((size_t)b * Nq + q0 + mi * 16 + r16) * Dq + h * 64;
#pragma unroll
    for (int ot = 0; ot < 4; ot++) {
      union { bf16 h[4]; ushort4 u; } r4;
#pragma unroll
      for (int r = 0; r < 4; r++) r4.h[r] = (bf16)(o[mi][ot][r] * li);
      *(ushort4*)(att + rowoff + ot * 16 + 4 * g) = r4.u;
    }
  }
}

// ---------------- LayerNorm over D=512, one wave per row ----------------
template <bool WB>
__global__ __launch_bounds__(64) void k_ln(const float* __restrict__ in,
                                           const float* __restrict__ gamma,
                                           const float* __restrict__ beta,
                                           float* __restrict__ outf,
                                           bf16* __restrict__ outb) {
  const int row = blockIdx.x, lane = threadIdx.x;
  const float* p = in + (size_t)row * Dq + lane * 8;
  float4 a = *(const float4*)p;
  float4 c = *(const float4*)(p + 4);
  float vals[8] = {a.x, a.y, a.z, a.w, c.x, c.y, c.z, c.w};
  float s = 0.f, q = 0.f;
#pragma unroll
  for (int j = 0; j < 8; j++) { s += vals[j]; q += vals[j] * vals[j]; }
#pragma unroll
  for (int off = 1; off < 64; off <<= 1) {
    s += __shfl_xor(s, off);
    q += __shfl_xor(q, off);
  }
  float mean = s * (1.f / Dq);
  float var = q * (1.f / Dq) - mean * mean;
  float rstd = rsqrtf(var + 1e-5f);
  float of[8];
#pragma unroll
  for (int j = 0; j < 8; j++) {
    int col = lane * 8 + j;
    of[j] = (vals[j] - mean) * rstd * gamma[col] + beta[col];
  }
  float4* op = (float4*)(outf + (size_t)row * Dq + lane * 8);
  op[0] = make_float4(of[0], of[1], of[2], of[3]);
  op[1] = make_float4(of[4], of[5], of[6], of[7]);
  if (WB) {
    union { bf16 h[8]; ushort4 u[2]; } rr;
#pragma unroll
    for (int j = 0; j < 8; j++) rr.h[j] = (bf16)of[j];
    ushort4* ob = (ushort4*)(outb + (size_t)row * Dq + lane * 8);
    ob[0] = rr.u[0];
    ob[1] = rr.u[1];
  }
}

extern "C" void kernel_launch(void* const* d_in, const int* in_sizes, int n_in,
                              void* d_out, int out_size, void* d_ws, size_t ws_size,
                              hipStream_t stream) {
  const float* x      = (const float*)d_in[0];
  const float* w_qkv  = (const float*)d_in[1];
  const float* b_qkv  = (const float*)d_in[2];
  const float* w_proj = (const float*)d_in[3];
  const float* b_proj = (const float*)d_in[4];
  const float* ln1_g  = (const float*)d_in[5];
  const float* ln1_b  = (const float*)d_in[6];
  const float* w1     = (const float*)d_in[7];
  const float* b1     = (const float*)d_in[8];
  const float* w2     = (const float*)d_in[9];
  const float* b2     = (const float*)d_in[10];
  const float* ln2_g  = (const float*)d_in[11];
  const float* ln2_b  = (const float*)d_in[12];
  float* out = (float*)d_out;

  const int M = Bq * Nq;  // 8192 rows

  char* p = (char*)d_ws;
  auto alloc = [&](size_t bytes) -> void* {
    char* r = p;
    p += (bytes + 255) & ~(size_t)255;
    return (void*)r;
  };
  bf16* xb     = (bf16*)alloc((size_t)M * Dq * 2);        // x bf16; later reused as att
  bf16* qkvb   = (bf16*)alloc((size_t)M * 3 * Dq * 2);
  bf16* wqkvT  = (bf16*)alloc((size_t)3 * Dq * Dq * 2);
  bf16* wprojT = (bf16*)alloc((size_t)Dq * Dq * 2);
  bf16* w1T    = (bf16*)alloc((size_t)Hq * Dq * 2);
  bf16* w2T    = (bf16*)alloc((size_t)Dq * Hq * 2);
  float* y1    = (float*)alloc((size_t)M * Dq * 4);       // also y2
  float* x1f   = (float*)alloc((size_t)M * Dq * 4);
  bf16* x1b    = (bf16*)alloc((size_t)M * Dq * 2);
  bf16* hb     = (bf16*)alloc((size_t)M * Hq * 2);
  bf16* attb   = xb;   // alias: xb consumed by qkv GEMM before attention writes
  bf16* vtb    = hb;   // alias: hb written by ffn1 only after attention is done

  dim3 tb(32, 8);
  k_cvt_bf16<<<(M * Dq / 4 + 255) / 256, 256, 0, stream>>>(x, xb, M * Dq);
  k_transpose_cvt<<<dim3((3 * Dq) / 32, Dq / 32), tb, 0, stream>>>(w_qkv, wqkvT, Dq, 3 * Dq);
  k_transpose_cvt<<<dim3(Dq / 32, Dq / 32), tb, 0, stream>>>(w_proj, wprojT, Dq, Dq);
  k_transpose_cvt<<<dim3(Hq / 32, Dq / 32), tb, 0, stream>>>(w1, w1T, Dq, Hq);
  k_transpose_cvt<<<dim3(Dq / 32, Hq / 32), tb, 0, stream>>>(w2, w2T, Hq, Dq);

  // qkv = x @ w_qkv + b_qkv
  k_gemm<128, false, false, true><<<dim3((3 * Dq) / 128, M / 128), 512, 0, stream>>>(
      xb, wqkvT, b_qkv, nullptr, qkvb, M, 3 * Dq, Dq);
  // vt = transpose+interleave of V part
  k_vtrans<<<dim3(Nq / 64, Bq * HEADS), 256, 0, stream>>>(qkvb, vtb);
  // attention
  k_attn<<<dim3(Bq * HEADS, Nq / 128), 256, 0, stream>>>(qkvb, vtb, attb);
  // y1 = att @ w_proj + b_proj + x
  k_gemm<64, false, true, false><<<dim3(Dq / 128, M / 64), 512, 0, stream>>>(
      attb, wprojT, b_proj, x, y1, M, Dq, Dq);
  // x1 = LN1(y1) -> fp32 + bf16
  k_ln<true><<<M, 64, 0, stream>>>(y1, ln1_g, ln1_b, x1f, x1b);
  // h = gelu(x1 @ w1 + b1)
  k_gemm<128, true, false, true><<<dim3(Hq / 128, M / 128), 512, 0, stream>>>(
      x1b, w1T, b1, nullptr, hb, M, Hq, Dq);
  // y2 = h @ w2 + b2 + x1
  k_gemm<64, false, true, false><<<dim3(Dq / 128, M / 64), 512, 0, stream>>>(
      hb, w2T, b2, x1f, y1, M, Dq, Hq);
  // out = LN2(y2)
  k_ln<false><<<M, 64, 0, stream>>>(y1, ln2_g, ln2_b, out, nullptr);
}